// Round 1
// baseline (167.112 us; speedup 1.0000x reference)
//
#include <hip/hip_runtime.h>

// Fixed problem geometry from setup_inputs():
//   input  (1, C=16, H=16, W=16)  -> N_in  = 4096
//   kernel (O=32, C=16, 3, 3), pad=1, stride=1 -> H'=W'=16, N_out = 8192
#define O_CH  32
#define C_CH  16
#define HH    16
#define WW    16
#define NPIX  256     // H*W
#define NIN   4096    // C*H*W
#define NOUT  8192    // O*H'*W'

// ---------------------------------------------------------------------------
// Kernel 1: x_out / lb_new / ub_new  (8192 outputs each)
// Sign-split interval propagation, exact reference math:
//   lb = conv(ub, w<0) + conv(lb, w>=0) + 3b
//   ub = conv(lb, w<0) + conv(ub, w>=0) + 3b
//   x  = conv(x, w) + b
// ---------------------------------------------------------------------------
__global__ void conv_bounds_kernel(const float* __restrict__ x,
                                   const float* __restrict__ lb,
                                   const float* __restrict__ ub,
                                   const float* __restrict__ wk,
                                   const float* __restrict__ bias,
                                   float* __restrict__ out) {
    int t = blockIdx.x * blockDim.x + threadIdx.x;
    if (t >= NOUT) return;
    int o  = t >> 8;          // output channel
    int ph = (t >> 4) & 15;   // output row
    int pw = t & 15;          // output col
    float xa = 0.f, la = 0.f, ua = 0.f;
    #pragma unroll
    for (int c = 0; c < C_CH; ++c) {
        const float* kb = wk + (o * C_CH + c) * 9;
        #pragma unroll
        for (int kh = 0; kh < 3; ++kh) {
            int h = ph + kh - 1;
            if ((unsigned)h >= (unsigned)HH) continue;
            #pragma unroll
            for (int kw = 0; kw < 3; ++kw) {
                int w = pw + kw - 1;
                if ((unsigned)w >= (unsigned)WW) continue;
                float k = kb[kh * 3 + kw];
                int idx = c * NPIX + h * WW + w;
                float xv = x[idx];
                float lv = lb[idx];
                float uv = ub[idx];
                xa = fmaf(k, xv, xa);
                if (k < 0.f) {
                    la = fmaf(k, uv, la);
                    ua = fmaf(k, lv, ua);
                } else {
                    la = fmaf(k, lv, la);
                    ua = fmaf(k, uv, ua);
                }
            }
        }
    }
    float b = bias[o];
    out[t]            = xa + b;        // x_out
    out[NOUT + t]     = la + 3.f * b;  // lb_new
    out[2 * NOUT + t] = ua + 3.f * b;  // ub_new
}

// ---------------------------------------------------------------------------
// Kernel 2: unrolled weight matrix [NIN][NOUT] + bias_vec [NOUT]
//   weights[(c,h,w),(o,ph,pw)] = K[o,c,h-ph+1,w-pw+1] if offsets in [0,3) else 0
// Pure streaming-store kernel (float4, fully coalesced). The 18 KB kernel
// tensor is L1-resident; ~96% of outputs are zeros.
// ---------------------------------------------------------------------------
__global__ void weights_kernel(const float* __restrict__ wk,
                               const float* __restrict__ bias,
                               float* __restrict__ weights,
                               float* __restrict__ bias_vec) {
    const int total4 = NIN * (NOUT / 4);   // 8,388,608 float4 stores
    int stride = gridDim.x * blockDim.x;
    for (int i = blockIdx.x * blockDim.x + threadIdx.x; i < total4; i += stride) {
        int n  = i >> 11;        // input flat index (row), NOUT/4 = 2048
        int r  = i & 2047;       // float4 index within row
        int o  = r >> 6;         // 256/4 = 64 float4 per (o) plane
        int p  = r & 63;
        int ph = p >> 2;
        int pw0 = (p & 3) << 2;  // first pw of this float4 (row-aligned: 16%4==0)
        int c = n >> 8;
        int h = (n >> 4) & 15;
        int w = n & 15;
        float4 v = make_float4(0.f, 0.f, 0.f, 0.f);
        int kh = h - ph + 1;
        if ((unsigned)kh < 3u) {
            const float* kb = wk + ((o * C_CH + c) * 3 + kh) * 3;
            int kw0 = w - pw0 + 1;          // kw for lane j is kw0 - j
            if ((unsigned)(kw0)     < 3u) v.x = kb[kw0];
            if ((unsigned)(kw0 - 1) < 3u) v.y = kb[kw0 - 1];
            if ((unsigned)(kw0 - 2) < 3u) v.z = kb[kw0 - 2];
            if ((unsigned)(kw0 - 3) < 3u) v.w = kb[kw0 - 3];
        }
        reinterpret_cast<float4*>(weights)[i] = v;
    }
    // bias_vec: broadcast bias[o] over the 256 spatial positions
    int t = blockIdx.x * blockDim.x + threadIdx.x;
    if (t < NOUT) bias_vec[t] = bias[t >> 8];
}

extern "C" void kernel_launch(void* const* d_in, const int* in_sizes, int n_in,
                              void* d_out, int out_size, void* d_ws, size_t ws_size,
                              hipStream_t stream) {
    const float* x    = (const float*)d_in[0];
    const float* lbp  = (const float*)d_in[1];
    const float* ubp  = (const float*)d_in[2];
    // d_in[3] = input_shape (int32), geometry is compile-time fixed
    const float* wk   = (const float*)d_in[4];
    const float* bias = (const float*)d_in[5];

    float* out = (float*)d_out;
    float* x_out    = out;                       // 8192
    float* weights  = out + 3 * NOUT;            // 4096*8192
    float* bias_vec = out + 3 * NOUT + (size_t)NIN * NOUT; // 8192

    // Bounds + concrete forward: 8192 threads
    conv_bounds_kernel<<<NOUT / 256, 256, 0, stream>>>(x, lbp, ubp, wk, bias, x_out);

    // Weights matrix: grid-stride streaming stores (2048 blocks x 256 threads,
    // 16 float4 per thread)
    weights_kernel<<<2048, 256, 0, stream>>>(wk, bias, weights, bias_vec);
}

// Round 3
// 148.381 us; speedup vs baseline: 1.1262x; 1.1262x over previous
//
#include <hip/hip_runtime.h>

// Fixed geometry: input (1,16,16,16) -> NIN=4096; kernel (32,16,3,3), pad1 stride1 -> NOUT=8192
#define O_CH  32
#define C_CH  16
#define HH    16
#define WW    16
#define NPIX  256
#define NIN   4096
#define NOUT  8192
#define NB_BOUNDS  32
#define NB_WEIGHTS 2048   // 8 col-groups x 256 row-sets (16 rows each)

typedef float v4f __attribute__((ext_vector_type(4)));

// out layout (floats): x_out[8192] | lb[8192] | ub[8192] | weights[4096*8192] | bias_vec[8192]

__global__ __launch_bounds__(256) void fused_deeppoly_kernel(
    const float* __restrict__ x,
    const float* __restrict__ lb,
    const float* __restrict__ ub,
    const float* __restrict__ wk,
    const float* __restrict__ bias,
    float* __restrict__ out) {
    __shared__ float sx[NIN], sl[NIN], su[NIN], skw[C_CH * 9];
    const int b   = blockIdx.x;
    const int tid = threadIdx.x;

    if (b < NB_BOUNDS) {
        // ---------------- bounds + concrete forward + bias_vec ----------------
        // Block b owns output channel o=b (256 spatial outputs, one per thread).
        const v4f* x4 = (const v4f*)x;
        const v4f* l4 = (const v4f*)lb;
        const v4f* u4 = (const v4f*)ub;
        v4f* sx4 = (v4f*)sx; v4f* sl4 = (v4f*)sl; v4f* su4 = (v4f*)su;
        #pragma unroll
        for (int k = 0; k < 4; ++k) {
            int i = tid + k * 256;           // 1024 float4 per array
            sx4[i] = x4[i]; sl4[i] = l4[i]; su4[i] = u4[i];
        }
        const int o = b;
        if (tid < C_CH * 9) skw[tid] = wk[o * C_CH * 9 + tid];
        __syncthreads();

        const int ph = tid >> 4, pw = tid & 15;
        float xa = 0.f, la = 0.f, ua = 0.f;
        #pragma unroll
        for (int c = 0; c < C_CH; ++c) {
            #pragma unroll
            for (int kh = 0; kh < 3; ++kh) {
                int h = ph + kh - 1;
                if ((unsigned)h >= (unsigned)HH) continue;
                #pragma unroll
                for (int kw = 0; kw < 3; ++kw) {
                    int w = pw + kw - 1;
                    if ((unsigned)w >= (unsigned)WW) continue;
                    float k   = skw[c * 9 + kh * 3 + kw];
                    int   idx = c * NPIX + h * WW + w;
                    xa = fmaf(k, sx[idx], xa);
                    float lv = sl[idx], uv = su[idx];
                    la = fmaf(k, (k < 0.f) ? uv : lv, la);
                    ua = fmaf(k, (k < 0.f) ? lv : uv, ua);
                }
            }
        }
        const int   t  = o * 256 + tid;
        const float bv = bias[o];
        out[t]            = xa + bv;         // x_out   (bias once)
        out[NOUT + t]     = la + 3.f * bv;   // lb_new  (bias 3x, per reference)
        out[2 * NOUT + t] = ua + 3.f * bv;   // ub_new
        out[(size_t)3 * NOUT + (size_t)NIN * NOUT + t] = bv;  // bias_vec
    } else {
        // ---------------- unrolled weight matrix [NIN rows][NOUT cols] ----------------
        // weights[n=(c,h,w)][col=(o,ph,pw)] = K[o,c,h-ph+1,w-pw+1] if offsets in [0,3)
        // Thread owns one float4-column r for 16 consecutive rows; within those rows
        // c,h are fixed and w==j slides 0..15, so the float4 is a sliding window
        // over (k0,k1,k2): 1 select + 3 moves + 1 nontemporal store per row.
        const int b2       = b - NB_BOUNDS;
        const int colgroup = b2 & 7;          // 8 groups of 256 float4 across a row
        const int rowset   = b2 >> 3;         // 256 row-sets of 16 rows
        const int r   = colgroup * 256 + tid; // float4 index within a row (0..2047)
        const int o   = r >> 6;
        const int p   = r & 63;
        const int ph  = p >> 2;
        const int pw0 = (p & 3) << 2;
        const int c   = rowset >> 4;
        const int h   = rowset & 15;
        const int kh  = h - ph + 1;

        float k0 = 0.f, k1 = 0.f, k2 = 0.f;
        if ((unsigned)kh < 3u) {
            const float* kb = wk + ((o * C_CH + c) * 3 + kh) * 3;
            k0 = kb[0]; k1 = kb[1]; k2 = kb[2];
        }
        auto sel = [&](int kw) -> float {
            return kw == 0 ? k0 : (kw == 1 ? k1 : (kw == 2 ? k2 : 0.f));
        };

        v4f* wout = (v4f*)(out + 3 * NOUT);
        v4f* pptr = wout + (size_t)(rowset * 16) * 2048 + r;

        v4f v;
        v.x = sel(1 - pw0);
        v.y = sel(-pw0);
        v.z = sel(-1 - pw0);
        v.w = sel(-2 - pw0);
        #pragma unroll
        for (int j = 0; j < 16; ++j) {
            __builtin_nontemporal_store(v, pptr);
            pptr += 2048;
            v.w = v.z; v.z = v.y; v.y = v.x;
            v.x = sel(j + 2 - pw0);
        }
    }
}

extern "C" void kernel_launch(void* const* d_in, const int* in_sizes, int n_in,
                              void* d_out, int out_size, void* d_ws, size_t ws_size,
                              hipStream_t stream) {
    const float* x    = (const float*)d_in[0];
    const float* lbp  = (const float*)d_in[1];
    const float* ubp  = (const float*)d_in[2];
    // d_in[3] = input_shape (int32), geometry compile-time fixed
    const float* wk   = (const float*)d_in[4];
    const float* bias = (const float*)d_in[5];

    fused_deeppoly_kernel<<<NB_BOUNDS + NB_WEIGHTS, 256, 0, stream>>>(
        x, lbp, ubp, wk, bias, (float*)d_out);
}